// Round 2
// 3433.430 us; speedup vs baseline: 1.4322x; 1.4322x over previous
//
#include <hip/hip_runtime.h>
#include <cstdint>
#include <cstddef>

typedef unsigned short ushort_t;
typedef __attribute__((ext_vector_type(4))) float f4;
typedef __attribute__((ext_vector_type(8))) short s8v;
typedef __attribute__((ext_vector_type(4))) short s4v;
typedef __attribute__((ext_vector_type(4))) unsigned short us4;

typedef const __attribute__((address_space(1))) void* gptr_t;
typedef __attribute__((address_space(3))) void* lptr_t;

#define DEV __device__ __forceinline__

enum { TT = 8192, HH = 2048, NHq = 16, NKVq = 8, DHq = 128, FF = 8192, SS = 1024, BBq = 8,
       QKVROW = 4096 };

DEV float bf2f(ushort_t u) { union { unsigned int i; float f; } x; x.i = ((unsigned int)u) << 16; return x.f; }
DEV ushort_t f2bf(float f) {
  union { float f; unsigned int i; } x; x.f = f;
  unsigned int r = x.i + 0x7fffu + ((x.i >> 16) & 1u);
  return (ushort_t)(r >> 16);
}

#define MFMA_BF16(a, b, c) __builtin_amdgcn_mfma_f32_16x16x32_bf16((a), (b), (c), 0, 0, 0)

// ---------------- RMSNorm over H=2048, one row per block (256 thr) ----------------
template <int BF16_OUT>
__global__ __launch_bounds__(256) void rms_kernel(const float* __restrict__ x,
                                                  const float* __restrict__ wgt,
                                                  void* __restrict__ out)
{
  __shared__ float red[4];
  const int t = threadIdx.x, lane = t & 63, w = t >> 6;
  const size_t row = blockIdx.x;
  const float* xr = x + row * HH;
  f4 v0 = *(const f4*)(xr + t * 4);
  f4 v1 = *(const f4*)(xr + 1024 + t * 4);
  float ss = v0[0]*v0[0] + v0[1]*v0[1] + v0[2]*v0[2] + v0[3]*v0[3]
           + v1[0]*v1[0] + v1[1]*v1[1] + v1[2]*v1[2] + v1[3]*v1[3];
#pragma unroll
  for (int off = 1; off < 64; off <<= 1) ss += __shfl_xor(ss, off);
  if (lane == 0) red[w] = ss;
  __syncthreads();
  const float tot = red[0] + red[1] + red[2] + red[3];
  const float r = rsqrtf(tot * (1.0f / (float)HH) + 1e-6f);
  f4 w0 = *(const f4*)(wgt + t * 4);
  f4 w1 = *(const f4*)(wgt + 1024 + t * 4);
  if (BF16_OUT) {
    ushort_t* ob = (ushort_t*)out;
    us4 a, b;
#pragma unroll
    for (int i = 0; i < 4; ++i) { a[i] = f2bf(v0[i] * r * w0[i]); b[i] = f2bf(v1[i] * r * w1[i]); }
    *(us4*)(ob + row * HH + t * 4) = a;
    *(us4*)(ob + row * HH + 1024 + t * 4) = b;
  } else {
    float* of = (float*)out;
    f4 a, b;
#pragma unroll
    for (int i = 0; i < 4; ++i) { a[i] = v0[i] * r * w0[i]; b[i] = v1[i] * r * w1[i]; }
    *(f4*)(of + row * HH + t * 4) = a;
    *(f4*)(of + row * HH + 1024 + t * 4) = b;
  }
}

// ---------------- fp32 [K][N] -> bf16 B^T [N][K] (32x32 LDS transpose) ----------------
__global__ __launch_bounds__(256) void wcvt_kernel(const float* __restrict__ w,
                                                   ushort_t* __restrict__ o, int K, int N)
{
  __shared__ float tile[32][33];
  const int t = threadIdx.x, ty = t >> 3, tx = t & 7;
  const int n0 = blockIdx.x * 32, k0 = blockIdx.y * 32;
  f4 ld = *(const f4*)(w + (size_t)(k0 + ty) * N + n0 + tx * 4);
#pragma unroll
  for (int i = 0; i < 4; ++i) tile[ty][tx * 4 + i] = ld[i];
  __syncthreads();
  us4 st;
#pragma unroll
  for (int i = 0; i < 4; ++i) st[i] = f2bf(tile[tx * 4 + i][ty]);
  *(us4*)(o + (size_t)(n0 + ty) * K + k0 + tx * 4) = st;
}

// ---------------- v (qkv cols [3072,4096)) bf16 -> vT [(b*NKV+kvh)][DH][S] ----------------
__global__ __launch_bounds__(256) void vtrans_kernel(const ushort_t* __restrict__ v,
                                                     ushort_t* __restrict__ vt)
{
  __shared__ ushort_t tile[32][40];
  const int t = threadIdx.x, ty = t >> 3, tx = t & 7;
  const int s0 = blockIdx.x * 32, d0 = blockIdx.y * 32;
  const int b = blockIdx.z >> 3, kvh = blockIdx.z & 7;
  us4 ld = *(const us4*)(v + (size_t)(b * SS + s0 + ty) * QKVROW + kvh * DHq + d0 + tx * 4);
#pragma unroll
  for (int i = 0; i < 4; ++i) tile[ty][tx * 4 + i] = ld[i];
  __syncthreads();
  us4 st;
#pragma unroll
  for (int i = 0; i < 4; ++i) st[i] = tile[tx * 4 + i][ty];
  *(us4*)(vt + ((size_t)(b * NKVq + kvh) * DHq + d0 + ty) * SS + s0 + tx * 4) = st;
}

// ---------------- per-(token,head) RMS over DH=128 + RoPE (in place, bf16, strided) ----------------
__global__ __launch_bounds__(256) void qkrope_kernel(ushort_t* __restrict__ buf,
                                                     const float* __restrict__ nw,
                                                     const int* __restrict__ pids,
                                                     int nh, int rowlen, float scale)
{
  const int w = threadIdx.x >> 6, lane = threadIdx.x & 63;
  const int idx = blockIdx.x * 4 + w;
  const int t = idx / nh;
  const int h = idx - t * nh;
  ushort_t* p = buf + (size_t)t * rowlen + (size_t)h * DHq;
  float a = bf2f(p[lane]), b = bf2f(p[lane + 64]);
  float ss = a * a + b * b;
#pragma unroll
  for (int off = 1; off < 64; off <<= 1) ss += __shfl_xor(ss, off);
  const float r = rsqrtf(ss * (1.0f / (float)DHq) + 1e-6f);
  const float na = a * r * nw[lane], nb = b * r * nw[lane + 64];
  const float pos = (float)(pids[t] % SS);
  const float invf = exp2f((float)lane * -0.31143075889163463f);  // 1e6^(-lane/64)
  const float fr = pos * invf;
  const float c = cosf(fr), s = sinf(fr);
  p[lane]      = f2bf((na * c - nb * s) * scale);
  p[lane + 64] = f2bf((nb * c + na * s) * scale);
}

// ---------------- 256x256 8-phase GEMM: C[M,N] = A[M,K] * B^T[N,K]^T ----------------
// 512 thr / 8 waves (2M x 4N), BK=64, LDS 128 KiB double-buffered, XOR-swizzled
// (swizzle applied on the GLOBAL source address of global_load_lds; same XOR on ds_read).
// Per-phase fence discipline matches the verified m201 template:
//   {ds_read subtile || STAGE prefetch} -> s_barrier -> s_waitcnt lgkmcnt(0) ["memory"]
//   -> setprio(1) MFMA setprio(0) -> [vmcnt(4) at phase 3 only, "memory"] -> s_barrier
// Pipeline ledger (loads counted per thread, 2 per half-tile stage):
//   invariant at boundary into tile kt: tile kt fully landed; in flight = (kt+1).{B0,B1}.
//   tile kt phases stage: ph0 -> (kt+1).A0, ph1 -> (kt+1).A1, ph2 -> (kt+2).B0, ph3 -> (kt+2).B1
//   boundary wait: vmcnt(4) (retires (kt+1).{B0,B1,A0,A1}) -- never 0 in steady state.
// EPI 0: store bf16; EPI 1: fp32 C += ; EPI 2: C = silu(Gsrc) * acc (bf16)
template <int EPI>
__global__ __launch_bounds__(512, 2) void gemm256_kernel(
    const ushort_t* __restrict__ A, const ushort_t* __restrict__ BT,
    void* __restrict__ C, int M, int N, int K, const ushort_t* __restrict__ Gsrc)
{
  __shared__ __attribute__((aligned(16))) ushort_t As[2][256 * 64];
  __shared__ __attribute__((aligned(16))) ushort_t Bs[2][256 * 64];
  const int t = threadIdx.x;
  const int lane = t & 63;
  const int lr = lane & 15, lq = lane >> 4;
  const int w = t >> 6;
  const int wm = w >> 2, wn = w & 3;

  // XCD-aware bijective swizzle (all grids here have nwg % 8 == 0)
  const int Mt = M >> 8;
  const int nwg = Mt * (N >> 8);
  int lin = blockIdx.y * gridDim.x + blockIdx.x;
  lin = (lin & 7) * (nwg >> 3) + (lin >> 3);
  const int m0 = (lin % Mt) << 8, n0 = (lin / Mt) << 8;

  const ushort_t* gA = A + (size_t)m0 * K;
  const ushort_t* gB = BT + (size_t)n0 * K;
  const int NT = K >> 6;

#define STAGE(GB, RB, LDSB, KT) do {                                                   \
    const int kc_ = (KT) << 6;                                                         \
    _Pragma("unroll")                                                                  \
    for (int j_ = 0; j_ < 2; ++j_) {                                                   \
      const int idx_ = j_ * 512 + t;                                                   \
      const int rr_ = idx_ >> 3, ss_ = idx_ & 7;                                       \
      const ushort_t* g_ = (GB) + (size_t)((RB) + rr_) * K + kc_ + ((ss_ ^ (rr_ & 7)) << 3); \
      __builtin_amdgcn_global_load_lds((gptr_t)g_, (lptr_t)((LDSB) + idx_ * 8), 16, 0, 0); \
    } } while (0)

  // prologue: tile0 full + tile1 B-halves -> leaves tile1.{B0,B1} in flight
  STAGE(gA, 0,   &As[0][0],    0);
  STAGE(gA, 128, &As[0][8192], 0);
  STAGE(gB, 0,   &Bs[0][0],    0);
  STAGE(gB, 128, &Bs[0][8192], 0);
  STAGE(gB, 0,   &Bs[1][0],    1);
  STAGE(gB, 128, &Bs[1][8192], 1);
  asm volatile("s_waitcnt vmcnt(4)" ::: "memory");
  __builtin_amdgcn_s_barrier();

  f4 acc[8][4] = {};

  for (int kt = 0; kt < NT; ++kt) {
    const int p = kt & 1;
    const ushort_t* as = &As[p][0];
    const ushort_t* bs = &Bs[p][0];
    s8v bfr[4][2];
#pragma unroll
    for (int q = 0; q < 4; ++q) {
      if (q == 0) {
#pragma unroll
        for (int ni = 0; ni < 4; ++ni) {
          const int row = wn * 64 + ni * 16 + lr;
          bfr[ni][0] = *(const s8v*)(bs + row * 64 + ((lq ^ (lr & 7)) << 3));
          bfr[ni][1] = *(const s8v*)(bs + row * 64 + (((4 + lq) ^ (lr & 7)) << 3));
        }
      }
      s8v a0k0, a0k1, a1k0, a1k1;
      {
        const int r0 = wm * 128 + (2 * q) * 16 + lr;
        const int r1 = r0 + 16;
        a0k0 = *(const s8v*)(as + r0 * 64 + ((lq ^ (lr & 7)) << 3));
        a0k1 = *(const s8v*)(as + r0 * 64 + (((4 + lq) ^ (lr & 7)) << 3));
        a1k0 = *(const s8v*)(as + r1 * 64 + ((lq ^ (lr & 7)) << 3));
        a1k1 = *(const s8v*)(as + r1 * 64 + (((4 + lq) ^ (lr & 7)) << 3));
      }
      if (q == 0) { if (kt + 1 < NT) STAGE(gA, 0,   &As[p ^ 1][0],    kt + 1); }
      if (q == 1) { if (kt + 1 < NT) STAGE(gA, 128, &As[p ^ 1][8192], kt + 1); }
      if (q == 2) { if (kt + 2 < NT) STAGE(gB, 0,   &Bs[p][0],        kt + 2); }
      if (q == 3) { if (kt + 2 < NT) STAGE(gB, 128, &Bs[p][8192],     kt + 2); }
      __builtin_amdgcn_s_barrier();
      asm volatile("s_waitcnt lgkmcnt(0)" ::: "memory");
      __builtin_amdgcn_s_setprio(1);
#pragma unroll
      for (int ni = 0; ni < 4; ++ni) {
        acc[2 * q][ni]     = MFMA_BF16(a0k0, bfr[ni][0], acc[2 * q][ni]);
        acc[2 * q][ni]     = MFMA_BF16(a0k1, bfr[ni][1], acc[2 * q][ni]);
        acc[2 * q + 1][ni] = MFMA_BF16(a1k0, bfr[ni][0], acc[2 * q + 1][ni]);
        acc[2 * q + 1][ni] = MFMA_BF16(a1k1, bfr[ni][1], acc[2 * q + 1][ni]);
      }
      __builtin_amdgcn_s_setprio(0);
      if (q == 3) {
        if (kt + 2 < NT) { asm volatile("s_waitcnt vmcnt(4)" ::: "memory"); }
        else             { asm volatile("s_waitcnt vmcnt(0)" ::: "memory"); }
      }
      __builtin_amdgcn_s_barrier();
    }
  }
#undef STAGE

  const int crow = m0 + wm * 128 + lq * 4;
  const int ccol = n0 + wn * 64 + lr;
  if (EPI == 0) {
    ushort_t* Cb = (ushort_t*)C;
#pragma unroll
    for (int mi = 0; mi < 8; ++mi)
#pragma unroll
      for (int ni = 0; ni < 4; ++ni)
#pragma unroll
        for (int r = 0; r < 4; ++r)
          Cb[(size_t)(crow + mi * 16 + r) * N + ccol + ni * 16] = f2bf(acc[mi][ni][r]);
  } else if (EPI == 1) {
    float* Cf = (float*)C;
#pragma unroll
    for (int mi = 0; mi < 8; ++mi)
#pragma unroll
      for (int ni = 0; ni < 4; ++ni)
#pragma unroll
        for (int r = 0; r < 4; ++r) {
          const size_t o = (size_t)(crow + mi * 16 + r) * N + ccol + ni * 16;
          Cf[o] += acc[mi][ni][r];
        }
  } else {
    ushort_t* Cb = (ushort_t*)C;
#pragma unroll
    for (int mi = 0; mi < 8; ++mi)
#pragma unroll
      for (int ni = 0; ni < 4; ++ni)
#pragma unroll
        for (int r = 0; r < 4; ++r) {
          const size_t o = (size_t)(crow + mi * 16 + r) * N + ccol + ni * 16;
          const float g = bf2f(Gsrc[o]);
          const float sg = g / (1.0f + exp2f(-g * 1.4426950408889634f));
          Cb[o] = f2bf(sg * acc[mi][ni][r]);
        }
  }
}

// ---------------- Flash attention v2: LDS-staged K/V tiles, S^T = K*Q^T ----------------
// q/k live in the fused qkv buffer (row stride 4096); k pointer is pre-offset by +2048.
__global__ __launch_bounds__(256) void flash_kernel(
    const ushort_t* __restrict__ q, const ushort_t* __restrict__ k,
    const ushort_t* __restrict__ vt, ushort_t* __restrict__ attn)
{
  __shared__ __attribute__((aligned(16))) ushort_t Ks[64 * 128];  // [key][dh], 16B-swizzled
  __shared__ __attribute__((aligned(16))) ushort_t Vs[128 * 64];  // [dh][key], 16B-swizzled
  __shared__ __attribute__((aligned(16))) ushort_t plds[4][16][64];  // per-wave P^T, swizzled
  const int t = threadIdx.x;
  const int w = t >> 6, lane = t & 63;
  const int lq = lane >> 4, lr = lane & 15;
  const int b = blockIdx.z, h = blockIdx.y, kvh = h >> 1;
  const int qtile = gridDim.x - 1 - blockIdx.x;  // heavy tiles dispatch first
  const int q0 = qtile * 64 + w * 16;

  s8v qf[4];
  const size_t qbase = (size_t)(b * SS + q0 + lr) * QKVROW + h * DHq;
#pragma unroll
  for (int kk = 0; kk < 4; ++kk)
    qf[kk] = *(const s8v*)(q + qbase + kk * 32 + lq * 8);

  f4 o[8] = {};
  float mprev = -3e38f, lsum = 0.0f;
  const int ntiles = qtile + 1;
  const size_t vbase = (size_t)(b * NKVq + kvh) * DHq * SS;

  for (int kt = 0; kt < ntiles; ++kt) {
    const int k0 = kt * 64;
#pragma unroll
    for (int it = 0; it < 4; ++it) {
      const int idx = it * 256 + t;
      const int krow = idx >> 4, kcol = (((idx & 15) ^ (krow & 15)) << 3);
      const ushort_t* gk = k + (size_t)(b * SS + k0 + krow) * QKVROW + kvh * DHq + kcol;
      __builtin_amdgcn_global_load_lds((gptr_t)gk, (lptr_t)(Ks + idx * 8), 16, 0, 0);
      const int vrow = idx >> 3, vcol = (((idx & 7) ^ (vrow & 7)) << 3);
      const ushort_t* gv = vt + vbase + (size_t)vrow * SS + k0 + vcol;
      __builtin_amdgcn_global_load_lds((gptr_t)gv, (lptr_t)(Vs + idx * 8), 16, 0, 0);
    }
    __syncthreads();

    f4 st[4];
#pragma unroll
    for (int sub = 0; sub < 4; ++sub) {
      f4 s = {};
#pragma unroll
      for (int kk = 0; kk < 4; ++kk) {
        s8v kf = *(const s8v*)(Ks + (sub * 16 + lr) * 128 + (((kk * 4 + lq) ^ (lr & 15)) << 3));
        s = MFMA_BF16(kf, qf[kk], s);
      }
      st[sub] = s;
    }

    float sv[16], tmax = -3e38f;
#pragma unroll
    for (int sub = 0; sub < 4; ++sub)
#pragma unroll
      for (int r = 0; r < 4; ++r) {
        const int key = k0 + sub * 16 + lq * 4 + r;
        const float v = (key <= q0 + lr) ? st[sub][r] : -3e38f;
        sv[sub * 4 + r] = v;
        tmax = fmaxf(tmax, v);
      }
    tmax = fmaxf(tmax, __shfl_xor(tmax, 16));
    tmax = fmaxf(tmax, __shfl_xor(tmax, 32));
    const float mnew = fmaxf(mprev, tmax);
    const float alpha = exp2f(mprev - mnew);
    float psum = 0.0f;
    ushort_t pb[16];
#pragma unroll
    for (int i = 0; i < 16; ++i) {
      const float pv = exp2f(sv[i] - mnew);
      psum += pv;
      pb[i] = f2bf(pv);
    }
    psum += __shfl_xor(psum, 16);
    psum += __shfl_xor(psum, 32);
    lsum = lsum * alpha + psum;
    mprev = mnew;
#pragma unroll
    for (int i = 0; i < 8; ++i) o[i] *= alpha;

#pragma unroll
    for (int sub = 0; sub < 4; ++sub) {
      s4v pv = { (short)pb[sub * 4 + 0], (short)pb[sub * 4 + 1],
                 (short)pb[sub * 4 + 2], (short)pb[sub * 4 + 3] };
      const int g = sub * 2 + (lq >> 1);
      *(s4v*)(&plds[w][lr][((g ^ (lr & 7)) << 3) + ((lq & 1) << 2)]) = pv;
    }
#pragma unroll
    for (int kq = 0; kq < 2; ++kq) {
      s8v pf = *(const s8v*)(&plds[w][lr][(((kq * 4 + lq) ^ (lr & 7)) << 3)]);
#pragma unroll
      for (int dt = 0; dt < 8; ++dt) {
        s8v vf = *(const s8v*)(Vs + (dt * 16 + lr) * 64 + (((kq * 4 + lq) ^ (lr & 7)) << 3));
        o[dt] = MFMA_BF16(vf, pf, o[dt]);
      }
    }
    __syncthreads();
  }

  const float inv = 1.0f / lsum;
  const size_t obase = (size_t)(b * SS + q0 + lr) * (NHq * DHq) + h * DHq;
#pragma unroll
  for (int dt = 0; dt < 8; ++dt)
#pragma unroll
    for (int r = 0; r < 4; ++r)
      attn[obase + dt * 16 + lq * 4 + r] = f2bf(o[dt][r] * inv);
}

// ============================= host =============================
extern "C" void kernel_launch(void* const* d_in, const int* in_sizes, int n_in,
                              void* d_out, int out_size, void* d_ws, size_t ws_size,
                              hipStream_t stream)
{
  const float* hid = (const float*)d_in[0];
  const int* pids  = (const int*)d_in[1];
  const float* ln1 = (const float*)d_in[3];
  const float* qw  = (const float*)d_in[4];
  const float* kw  = (const float*)d_in[5];
  const float* vw  = (const float*)d_in[6];
  const float* ow  = (const float*)d_in[7];
  const float* qnw = (const float*)d_in[8];
  const float* knw = (const float*)d_in[9];
  const float* ln2 = (const float*)d_in[10];
  const float* gw  = (const float*)d_in[11];
  const float* uw  = (const float*)d_in[12];
  const float* dw  = (const float*)d_in[13];
  const float* fw  = (const float*)d_in[14];

  char* p = (char*)d_ws;
  ushort_t* wA  = (ushort_t*)p; p += (size_t)32 << 20;  // weight staging (qkv/o/gate)
  ushort_t* wB  = (ushort_t*)p; p += (size_t)32 << 20;  // weight staging (up)
  ushort_t* wC  = (ushort_t*)p; p += (size_t)32 << 20;  // weight staging (down)
  ushort_t* hb  = (ushort_t*)p; p += (size_t)32 << 20;  // normed hidden, bf16 [T][H]
  ushort_t* qkv = (ushort_t*)p; p += (size_t)64 << 20;  // fused q|k|v, bf16 [T][4096]
  ushort_t* vtb = (ushort_t*)p; p += (size_t)16 << 20;  // v^T [(b,kvh)][DH][S]
  ushort_t* ab  = (ushort_t*)p; p += (size_t)32 << 20;  // attn out [T][NH*DH]
  p += (size_t)16 << 20;                                // tail pad for gbig
  ushort_t* gbig = qkv;  // [T][F] bf16 = 128 MiB, aliases qkv|vtb|ab|pad (dead in MLP)
  if (ws_size < (size_t)(p - (char*)d_ws)) return;      // fail loudly (poisoned d_out)
  if (in_sizes[0] != TT * HH) return;

  float* x = (float*)d_out;  // fp32 residual stream lives in d_out
  hipMemcpyAsync(x, hid, (size_t)TT * HH * sizeof(float), hipMemcpyDeviceToDevice, stream);

  // 1/sqrt(128) * log2(e): softmax runs in exp2 domain inside flash
  const float qscale = 0.08838834764831845f * 1.4426950408889634f;

  for (int l = 0; l < 2; ++l) {
    rms_kernel<1><<<TT, 256, 0, stream>>>(x, ln1 + (size_t)l * HH, hb);

    // fused QKV projection: B^T rows [0,2048)=Q, [2048,3072)=K, [3072,4096)=V
    wcvt_kernel<<<dim3(64, 64), 256, 0, stream>>>(qw + (size_t)l * HH * 2048, wA, HH, 2048);
    wcvt_kernel<<<dim3(32, 64), 256, 0, stream>>>(kw + (size_t)l * HH * 1024,
                                                  wA + (size_t)2048 * HH, HH, 1024);
    wcvt_kernel<<<dim3(32, 64), 256, 0, stream>>>(vw + (size_t)l * HH * 1024,
                                                  wA + (size_t)3072 * HH, HH, 1024);
    gemm256_kernel<0><<<dim3(32, 16), 512, 0, stream>>>(hb, wA, qkv, TT, QKVROW, HH, nullptr);

    qkrope_kernel<<<TT * NHq / 4, 256, 0, stream>>>(qkv, qnw + l * DHq, pids, NHq, QKVROW, qscale);
    qkrope_kernel<<<TT * NKVq / 4, 256, 0, stream>>>(qkv + 2048, knw + l * DHq, pids, NKVq, QKVROW, 1.0f);
    vtrans_kernel<<<dim3(32, 4, 64), 256, 0, stream>>>(qkv + 3072, vtb);
    flash_kernel<<<dim3(16, 16, 8), 256, 0, stream>>>(qkv, qkv + 2048, vtb, ab);

    wcvt_kernel<<<dim3(64, 64), 256, 0, stream>>>(ow + (size_t)l * 2048 * HH, wA, 2048, HH);
    gemm256_kernel<1><<<dim3(32, 8), 512, 0, stream>>>(ab, wA, x, TT, HH, 2048, nullptr);

    rms_kernel<1><<<TT, 256, 0, stream>>>(x, ln2 + (size_t)l * HH, hb);
    wcvt_kernel<<<dim3(256, 64), 256, 0, stream>>>(gw + (size_t)l * HH * FF, wA, HH, FF);
    wcvt_kernel<<<dim3(256, 64), 256, 0, stream>>>(uw + (size_t)l * HH * FF, wB, HH, FF);
    wcvt_kernel<<<dim3(64, 256), 256, 0, stream>>>(dw + (size_t)l * FF * HH, wC, FF, HH);
    // un-chunked MLP: full-M gemms (grids 1024/1024/256 blocks, all full-CU)
    gemm256_kernel<0><<<dim3(32, 32), 512, 0, stream>>>(hb, wA, gbig, TT, FF, HH, nullptr);
    gemm256_kernel<2><<<dim3(32, 32), 512, 0, stream>>>(hb, wB, gbig, TT, FF, HH, gbig);
    gemm256_kernel<1><<<dim3(32, 8), 512, 0, stream>>>(gbig, wC, x, TT, HH, FF, nullptr);
  }
  rms_kernel<0><<<TT, 256, 0, stream>>>(x, fw, x);  // in place: d_out -> d_out
}